// Round 1
// baseline (1294.895 us; speedup 1.0000x reference)
//
#include <hip/hip_runtime.h>

#define NN 100000
#define NE 3200000
#define NR 32
#define DIM 64

// ---------------- spmm1: side[row] += val * ego[col]  (64-wide, atomic) ----
__global__ __launch_bounds__(256) void spmm_main_kernel(
    const int* __restrict__ row, const int* __restrict__ col,
    const float* __restrict__ val, const float* __restrict__ ego,
    float* __restrict__ side)
{
    int gid = blockIdx.x * 256 + threadIdx.x;
    int e = gid >> 6;          // 4 edges per block
    int d = gid & 63;
    if (e >= NE) return;
    int r = row[e];
    int c = col[e];
    float v = val[e];
    atomicAdd(&side[r * DIM + d], v * ego[c * DIM + d]);
}

// ---------------- spmm2: coeff[row][rel] += val  (scalar atomic) ----------
__global__ __launch_bounds__(256) void spmm_rel_kernel(
    const int* __restrict__ row, const int* __restrict__ rel,
    const float* __restrict__ val, float* __restrict__ coeff)
{
    int e = blockIdx.x * 256 + threadIdx.x;
    if (e >= NE) return;
    atomicAdd(&coeff[row[e] * NR + rel[e]], val[e]);
}

// ---------------- epilogue: rel reconstruction + 2 matvecs + LReLU --------
// One wave per node-group; lane d owns output dim d.
__global__ __launch_bounds__(256) void finalize_kernel(
    const float* __restrict__ ego, const float* __restrict__ rel_emb,
    const float* __restrict__ side, const float* __restrict__ coeff,
    const float* __restrict__ W1, const float* __restrict__ b1,
    const float* __restrict__ W2, const float* __restrict__ b2,
    float* __restrict__ out)
{
    // LDS: transposed weights so lane-d reads sW[k*64+d] (consecutive -> 2-way, free)
    __shared__ float sW1t[DIM * DIM];
    __shared__ float sW2t[DIM * DIM];
    __shared__ float sRel[NR * DIM];

    for (int i = threadIdx.x; i < DIM * DIM; i += 256) {
        int dd = i >> 6;       // W row (output dim)
        int kk = i & 63;       // W col (input dim)
        sW1t[kk * DIM + dd] = W1[i];
        sW2t[kk * DIM + dd] = W2[i];
    }
    for (int i = threadIdx.x; i < NR * DIM; i += 256) sRel[i] = rel_emb[i];
    __syncthreads();

    const int wave = threadIdx.x >> 6;   // 0..3
    const int lane = threadIdx.x & 63;
    const int NPW  = 4;                  // nodes per wave
    int node0 = (blockIdx.x * 4 + wave) * NPW;

    float bb1 = b1[lane];
    float bb2 = b2[lane];

    for (int t = 0; t < NPW; ++t) {
        int n = node0 + t;
        if (n >= NN) return;             // uniform per wave

        float egod = ego[n * DIM + lane];
        float sd   = side[n * DIM + lane];

        // relation part: 0.1 * coeff[n,:] @ rel_emb
        float cv = (lane < NR) ? coeff[n * NR + lane] : 0.0f;
        float rp = 0.0f;
        #pragma unroll
        for (int r = 0; r < NR; ++r) {
            float c = __shfl(cv, r, 64);
            rp += c * sRel[r * DIM + lane];
        }
        sd += 0.1f * rp;

        float addv = egod + sd;          // ego + side
        float biv  = egod * sd;          // ego * side

        float acc1 = bb1;
        float acc2 = bb2;
        #pragma unroll
        for (int k = 0; k < DIM; ++k) {
            float a = __shfl(addv, k, 64);
            float b = __shfl(biv,  k, 64);
            acc1 += a * sW1t[k * DIM + lane];
            acc2 += b * sW2t[k * DIM + lane];
        }
        // leaky relu, slope 0.01
        acc1 = acc1 > 0.0f ? acc1 : 0.01f * acc1;
        acc2 = acc2 > 0.0f ? acc2 : 0.01f * acc2;
        out[n * DIM + lane] = acc1 + acc2;
    }
}

extern "C" void kernel_launch(void* const* d_in, const int* in_sizes, int n_in,
                              void* d_out, int out_size, void* d_ws, size_t ws_size,
                              hipStream_t stream)
{
    const float* ego   = (const float*)d_in[0];
    const float* rel   = (const float*)d_in[1];
    const int*   row   = (const int*)  d_in[2];
    const int*   col   = (const int*)  d_in[3];
    const float* vals  = (const float*)d_in[4];
    const int*   row_r = (const int*)  d_in[5];
    const int*   rel_i = (const int*)  d_in[6];
    const float* vals_r= (const float*)d_in[7];
    const float* W1    = (const float*)d_in[8];
    const float* b1    = (const float*)d_in[9];
    const float* W2    = (const float*)d_in[10];
    const float* b2    = (const float*)d_in[11];
    float* out = (float*)d_out;

    // workspace layout: side [NN*DIM] f32, coeff [NN*NR] f32
    float* side  = (float*)d_ws;
    float* coeff = side + (size_t)NN * DIM;
    size_t zero_bytes = ((size_t)NN * DIM + (size_t)NN * NR) * sizeof(float);
    hipMemsetAsync(d_ws, 0, zero_bytes, stream);

    // spmm1: NE edges x 64 dims, 4 edges per 256-thread block
    {
        int blocks = (NE * 64 + 255) / 256;  // 800000
        spmm_main_kernel<<<blocks, 256, 0, stream>>>(row, col, vals, ego, side);
    }
    // spmm2: scalar coefficient scatter
    {
        int blocks = (NE + 255) / 256;       // 12500
        spmm_rel_kernel<<<blocks, 256, 0, stream>>>(row_r, rel_i, vals_r, coeff);
    }
    // epilogue: 16 nodes per block (4 waves x 4 nodes)
    {
        int blocks = (NN + 15) / 16;         // 6250
        finalize_kernel<<<blocks, 256, 0, stream>>>(ego, rel, side, coeff,
                                                    W1, b1, W2, b2, out);
    }
}

// Round 2
// 1104.286 us; speedup vs baseline: 1.1726x; 1.1726x over previous
//
#include <hip/hip_runtime.h>
#include <hip/hip_fp16.h>

#define NN 100000
#define NE 3200000
#define NR 32
#define DIM 64
#define SCAN_BLK 1024
#define NBLK_SCAN ((NN + SCAN_BLK - 1) / SCAN_BLK)   // 98

// ---------------------------------------------------------------------------
// ws layout:
//   int    offsets[NN]          (degree -> exclusive scan -> mutated by scatter)
//   int    bsums[128]           (scan block sums)
//   float  coeff[NN*NR]         (per-node relation coefficients)
//   int    ecol[NE]             (CSR col indices)
//   __half eval[NE]             (CSR edge values, f16)
// total = 0.4M + 0.5K + 12.8M + 12.8M + 6.4M ~= 32.4 MB
// ---------------------------------------------------------------------------

// 1. histogram of main-edge rows + relation coefficient scatter
__global__ __launch_bounds__(256) void hist_kernel(
    const int* __restrict__ row,
    const int* __restrict__ row_r, const int* __restrict__ rel_i,
    const float* __restrict__ vals_r,
    int* __restrict__ offsets, float* __restrict__ coeff)
{
    int e = blockIdx.x * 256 + threadIdx.x;
    if (e >= NE) return;
    atomicAdd(&offsets[row[e]], 1);
    atomicAdd(&coeff[row_r[e] * NR + rel_i[e]], vals_r[e]);
}

// 2a. per-block inclusive scan -> exclusive in place, block totals out
__global__ __launch_bounds__(SCAN_BLK) void scan1_kernel(
    int* __restrict__ offsets, int* __restrict__ bsums)
{
    __shared__ int s[SCAN_BLK];
    int tid = threadIdx.x;
    int i = blockIdx.x * SCAN_BLK + tid;
    int v = (i < NN) ? offsets[i] : 0;
    s[tid] = v;
    __syncthreads();
    for (int off = 1; off < SCAN_BLK; off <<= 1) {
        int t = (tid >= off) ? s[tid - off] : 0;
        __syncthreads();
        s[tid] += t;
        __syncthreads();
    }
    if (i < NN) offsets[i] = s[tid] - v;              // exclusive
    if (tid == SCAN_BLK - 1) bsums[blockIdx.x] = s[tid];
}

// 2b. scan the (<=128) block sums, exclusive in place
__global__ __launch_bounds__(128) void scan2_kernel(int* __restrict__ bsums)
{
    __shared__ int s[128];
    int tid = threadIdx.x;
    int v = (tid < NBLK_SCAN) ? bsums[tid] : 0;
    s[tid] = v;
    __syncthreads();
    for (int off = 1; off < 128; off <<= 1) {
        int t = (tid >= off) ? s[tid - off] : 0;
        __syncthreads();
        s[tid] += t;
        __syncthreads();
    }
    if (tid < NBLK_SCAN) bsums[tid] = s[tid] - v;     // exclusive
}

// 2c. add block offsets
__global__ __launch_bounds__(SCAN_BLK) void scan3_kernel(
    int* __restrict__ offsets, const int* __restrict__ bsums)
{
    int i = blockIdx.x * SCAN_BLK + threadIdx.x;
    if (i < NN) offsets[i] += bsums[blockIdx.x];
}

// 3. scatter edges into CSR slots (mutates offsets -> segment ends)
__global__ __launch_bounds__(256) void scatter_kernel(
    const int* __restrict__ row, const int* __restrict__ col,
    const float* __restrict__ vals,
    int* __restrict__ offsets, int* __restrict__ ecol, __half* __restrict__ eval)
{
    int e = blockIdx.x * 256 + threadIdx.x;
    if (e >= NE) return;
    int pos = atomicAdd(&offsets[row[e]], 1);
    ecol[pos] = col[e];
    eval[pos] = __float2half(vals[e]);
}

// 4. per-node gather + rel reconstruction + matvecs + LReLU + store
//    one wave per node; lane d owns dim d. post-scatter: seg(n) = [off[n-1], off[n])
__global__ __launch_bounds__(256) void gather_finalize_kernel(
    const float* __restrict__ ego, const float* __restrict__ rel_emb,
    const int* __restrict__ offsets, const int* __restrict__ ecol,
    const __half* __restrict__ eval, const float* __restrict__ coeff,
    const float* __restrict__ W1, const float* __restrict__ b1,
    const float* __restrict__ W2, const float* __restrict__ b2,
    float* __restrict__ out)
{
    __shared__ float sW1t[DIM * DIM];
    __shared__ float sW2t[DIM * DIM];
    __shared__ float sRel[NR * DIM];

    for (int i = threadIdx.x; i < DIM * DIM; i += 256) {
        int dd = i >> 6, kk = i & 63;
        sW1t[kk * DIM + dd] = W1[i];
        sW2t[kk * DIM + dd] = W2[i];
    }
    for (int i = threadIdx.x; i < NR * DIM; i += 256) sRel[i] = rel_emb[i];
    __syncthreads();

    const int wave = threadIdx.x >> 6;
    const int lane = threadIdx.x & 63;
    const int NPW  = 4;
    int node0 = (blockIdx.x * 4 + wave) * NPW;

    float bb1 = b1[lane];
    float bb2 = b2[lane];

    for (int t = 0; t < NPW; ++t) {
        int n = node0 + t;
        if (n >= NN) return;                           // wave-uniform

        int start = (n > 0) ? offsets[n - 1] : 0;
        int end   = offsets[n];

        // ---- side = sum val * ego[col]  (registers, no atomics) ----
        float acc = 0.0f;
        for (int base = start; base < end; base += 64) {
            int idx = base + lane;
            int   c = 0;
            float v = 0.0f;
            if (idx < end) { c = ecol[idx]; v = __half2float(eval[idx]); }
            int m = min(64, end - base);
            for (int j = 0; j < m; ++j) {
                int   cc = __shfl(c, j, 64);
                float vv = __shfl(v, j, 64);
                acc += vv * ego[cc * DIM + lane];
            }
        }

        // ---- + 0.1 * coeff[n,:] @ rel_emb ----
        float cv = (lane < NR) ? coeff[n * NR + lane] : 0.0f;
        float rp = 0.0f;
        #pragma unroll
        for (int r = 0; r < NR; ++r) {
            float c = __shfl(cv, r, 64);
            rp += c * sRel[r * DIM + lane];
        }
        float sd = acc + 0.1f * rp;

        // ---- epilogue ----
        float egod = ego[n * DIM + lane];
        float addv = egod + sd;
        float biv  = egod * sd;

        float acc1 = bb1;
        float acc2 = bb2;
        #pragma unroll
        for (int k = 0; k < DIM; ++k) {
            float a = __shfl(addv, k, 64);
            float b = __shfl(biv,  k, 64);
            acc1 += a * sW1t[k * DIM + lane];
            acc2 += b * sW2t[k * DIM + lane];
        }
        acc1 = acc1 > 0.0f ? acc1 : 0.01f * acc1;
        acc2 = acc2 > 0.0f ? acc2 : 0.01f * acc2;
        out[n * DIM + lane] = acc1 + acc2;
    }
}

extern "C" void kernel_launch(void* const* d_in, const int* in_sizes, int n_in,
                              void* d_out, int out_size, void* d_ws, size_t ws_size,
                              hipStream_t stream)
{
    const float* ego   = (const float*)d_in[0];
    const float* rel   = (const float*)d_in[1];
    const int*   row   = (const int*)  d_in[2];
    const int*   col   = (const int*)  d_in[3];
    const float* vals  = (const float*)d_in[4];
    const int*   row_r = (const int*)  d_in[5];
    const int*   rel_i = (const int*)  d_in[6];
    const float* vals_r= (const float*)d_in[7];
    const float* W1    = (const float*)d_in[8];
    const float* b1    = (const float*)d_in[9];
    const float* W2    = (const float*)d_in[10];
    const float* b2    = (const float*)d_in[11];
    float* out = (float*)d_out;

    int*    offsets = (int*)d_ws;                     // NN
    int*    bsums   = offsets + NN;                   // 128
    float*  coeff   = (float*)(bsums + 128);          // NN*NR
    int*    ecol    = (int*)(coeff + (size_t)NN * NR);// NE
    __half* eval    = (__half*)(ecol + NE);           // NE

    // zero offsets + bsums + coeff (contiguous prefix)
    size_t zero_bytes = ((size_t)NN + 128 + (size_t)NN * NR) * sizeof(int);
    hipMemsetAsync(d_ws, 0, zero_bytes, stream);

    int eblocks = (NE + 255) / 256;                   // 12500
    hist_kernel<<<eblocks, 256, 0, stream>>>(row, row_r, rel_i, vals_r,
                                             offsets, coeff);
    scan1_kernel<<<NBLK_SCAN, SCAN_BLK, 0, stream>>>(offsets, bsums);
    scan2_kernel<<<1, 128, 0, stream>>>(bsums);
    scan3_kernel<<<NBLK_SCAN, SCAN_BLK, 0, stream>>>(offsets, bsums);
    scatter_kernel<<<eblocks, 256, 0, stream>>>(row, col, vals,
                                                offsets, ecol, eval);
    int gblocks = (NN + 15) / 16;                     // 6250
    gather_finalize_kernel<<<gblocks, 256, 0, stream>>>(
        ego, rel, offsets, ecol, eval, coeff, W1, b1, W2, b2, out);
}

// Round 3
// 986.633 us; speedup vs baseline: 1.3124x; 1.1192x over previous
//
#include <hip/hip_runtime.h>

#define NN 100000
#define NE 3200000
#define NR 32
#define DIM 64
#define SCAN_BLK 1024
#define NBLK_SCAN ((NN + SCAN_BLK - 1) / SCAN_BLK)   // 98

typedef unsigned long long u64;

// ---------------------------------------------------------------------------
// ws layout (38.8 MB):
//   int  offsets[NN]      degree -> exclusive scan -> mutated to seg ends
//   int  bsums[128]
//   float coeff[NN*NR]    per-node relation coefficients
//   u64  recs[NE]         CSR edge records {lo32: col, hi32: val f32 bits}
// ---------------------------------------------------------------------------

// 1. histogram of main-edge rows + relation coefficient scatter
__global__ __launch_bounds__(256) void hist_kernel(
    const int* __restrict__ row,
    const int* __restrict__ row_r, const int* __restrict__ rel_i,
    const float* __restrict__ vals_r,
    int* __restrict__ offsets, float* __restrict__ coeff)
{
    int e = blockIdx.x * 256 + threadIdx.x;
    if (e >= NE) return;
    atomicAdd(&offsets[row[e]], 1);
    atomicAdd(&coeff[row_r[e] * NR + rel_i[e]], vals_r[e]);
}

// 2a. per-block scan
__global__ __launch_bounds__(SCAN_BLK) void scan1_kernel(
    int* __restrict__ offsets, int* __restrict__ bsums)
{
    __shared__ int s[SCAN_BLK];
    int tid = threadIdx.x;
    int i = blockIdx.x * SCAN_BLK + tid;
    int v = (i < NN) ? offsets[i] : 0;
    s[tid] = v;
    __syncthreads();
    for (int off = 1; off < SCAN_BLK; off <<= 1) {
        int t = (tid >= off) ? s[tid - off] : 0;
        __syncthreads();
        s[tid] += t;
        __syncthreads();
    }
    if (i < NN) offsets[i] = s[tid] - v;              // exclusive
    if (tid == SCAN_BLK - 1) bsums[blockIdx.x] = s[tid];
}

// 2b. scan block sums
__global__ __launch_bounds__(128) void scan2_kernel(int* __restrict__ bsums)
{
    __shared__ int s[128];
    int tid = threadIdx.x;
    int v = (tid < NBLK_SCAN) ? bsums[tid] : 0;
    s[tid] = v;
    __syncthreads();
    for (int off = 1; off < 128; off <<= 1) {
        int t = (tid >= off) ? s[tid - off] : 0;
        __syncthreads();
        s[tid] += t;
        __syncthreads();
    }
    if (tid < NBLK_SCAN) bsums[tid] = s[tid] - v;     // exclusive
}

// 2c. add block offsets
__global__ __launch_bounds__(SCAN_BLK) void scan3_kernel(
    int* __restrict__ offsets, const int* __restrict__ bsums)
{
    int i = blockIdx.x * SCAN_BLK + threadIdx.x;
    if (i < NN) offsets[i] += bsums[blockIdx.x];
}

// 3. scatter edges into CSR slots as packed 8B records (one random store)
__global__ __launch_bounds__(256) void scatter_kernel(
    const int* __restrict__ row, const int* __restrict__ col,
    const float* __restrict__ vals,
    int* __restrict__ offsets, u64* __restrict__ recs)
{
    int e = blockIdx.x * 256 + threadIdx.x;
    if (e >= NE) return;
    int pos = atomicAdd(&offsets[row[e]], 1);
    union { float f; unsigned u; } uv; uv.f = vals[e];
    recs[pos] = ((u64)uv.u << 32) | (unsigned)(col[e]);
}

// 4. gather + rel reconstruction + matvecs + LReLU
//    one wave per 4 nodes; gather uses 4 groups of 16 lanes, each group
//    handling one edge per round with float4 ego loads.
__global__ __launch_bounds__(256) void gather_finalize_kernel(
    const float* __restrict__ ego, const float* __restrict__ rel_emb,
    const int* __restrict__ offsets, const u64* __restrict__ recs,
    const float* __restrict__ coeff,
    const float* __restrict__ W1, const float* __restrict__ b1,
    const float* __restrict__ W2, const float* __restrict__ b2,
    float* __restrict__ out)
{
    __shared__ float sW1t[DIM * DIM];
    __shared__ float sW2t[DIM * DIM];
    __shared__ float sRel[NR * DIM];

    for (int i = threadIdx.x; i < DIM * DIM; i += 256) {
        int dd = i >> 6, kk = i & 63;
        sW1t[kk * DIM + dd] = W1[i];
        sW2t[kk * DIM + dd] = W2[i];
    }
    for (int i = threadIdx.x; i < NR * DIM; i += 256) sRel[i] = rel_emb[i];
    __syncthreads();

    const int wave = threadIdx.x >> 6;
    const int lane = threadIdx.x & 63;
    const int g = lane >> 4;            // edge sub-group 0..3
    const int q = lane & 15;            // float4 chunk within the 64-dim row
    const int NPW = 4;
    int node0 = (blockIdx.x * 4 + wave) * NPW;

    const float4* ego4 = (const float4*)ego;
    float bb1 = b1[lane];
    float bb2 = b2[lane];

    for (int t = 0; t < NPW; ++t) {
        int n = node0 + t;
        if (n >= NN) return;                           // wave-uniform

        int start = (n > 0) ? offsets[n - 1] : 0;
        int end   = offsets[n];

        float4 acc0 = make_float4(0.f, 0.f, 0.f, 0.f);
        float4 acc1 = make_float4(0.f, 0.f, 0.f, 0.f);

        int e0 = start;
        // main: 8 edges per iteration (2 rounds of 4), unpredicated
        for (; e0 + 8 <= end; e0 += 8) {
            u64 rA = recs[e0 + g];
            u64 rB = recs[e0 + 4 + g];
            int   cA = (int)(unsigned)rA;
            float vA = __uint_as_float((unsigned)(rA >> 32));
            int   cB = (int)(unsigned)rB;
            float vB = __uint_as_float((unsigned)(rB >> 32));
            float4 a = ego4[(size_t)cA * 16 + q];
            float4 b = ego4[(size_t)cB * 16 + q];
            acc0.x += vA * a.x; acc0.y += vA * a.y;
            acc0.z += vA * a.z; acc0.w += vA * a.w;
            acc1.x += vB * b.x; acc1.y += vB * b.y;
            acc1.z += vB * b.z; acc1.w += vB * b.w;
        }
        // tail: up to 2 predicated rounds of 4
        for (; e0 < end; e0 += 4) {
            int e = e0 + g;
            if (e < end) {
                u64 rA = recs[e];
                int   cA = (int)(unsigned)rA;
                float vA = __uint_as_float((unsigned)(rA >> 32));
                float4 a = ego4[(size_t)cA * 16 + q];
                acc0.x += vA * a.x; acc0.y += vA * a.y;
                acc0.z += vA * a.z; acc0.w += vA * a.w;
            }
        }
        acc0.x += acc1.x; acc0.y += acc1.y;
        acc0.z += acc1.z; acc0.w += acc1.w;

        // reduce across the 4 edge groups (lanes with same q)
        acc0.x += __shfl_xor(acc0.x, 16, 64);
        acc0.y += __shfl_xor(acc0.y, 16, 64);
        acc0.z += __shfl_xor(acc0.z, 16, 64);
        acc0.w += __shfl_xor(acc0.w, 16, 64);
        acc0.x += __shfl_xor(acc0.x, 32, 64);
        acc0.y += __shfl_xor(acc0.y, 32, 64);
        acc0.z += __shfl_xor(acc0.z, 32, 64);
        acc0.w += __shfl_xor(acc0.w, 32, 64);

        // convert float4-in-16-lanes -> scalar lane layout (lane = dim)
        int src = lane >> 2;
        float sx = __shfl(acc0.x, src, 64);
        float sy = __shfl(acc0.y, src, 64);
        float sz = __shfl(acc0.z, src, 64);
        float sw = __shfl(acc0.w, src, 64);
        int cmp = lane & 3;
        float sd = (cmp == 0) ? sx : (cmp == 1) ? sy : (cmp == 2) ? sz : sw;

        // + 0.1 * coeff[n,:] @ rel_emb
        float cv = (lane < NR) ? coeff[n * NR + lane] : 0.0f;
        float rp = 0.0f;
        #pragma unroll
        for (int r = 0; r < NR; ++r) {
            float c = __shfl(cv, r, 64);
            rp += c * sRel[r * DIM + lane];
        }
        sd += 0.1f * rp;

        // epilogue
        float egod = ego[n * DIM + lane];
        float addv = egod + sd;
        float biv  = egod * sd;

        float acc1s = bb1;
        float acc2s = bb2;
        #pragma unroll
        for (int k = 0; k < DIM; ++k) {
            float a = __shfl(addv, k, 64);
            float b = __shfl(biv,  k, 64);
            acc1s += a * sW1t[k * DIM + lane];
            acc2s += b * sW2t[k * DIM + lane];
        }
        acc1s = acc1s > 0.0f ? acc1s : 0.01f * acc1s;
        acc2s = acc2s > 0.0f ? acc2s : 0.01f * acc2s;
        out[n * DIM + lane] = acc1s + acc2s;
    }
}

extern "C" void kernel_launch(void* const* d_in, const int* in_sizes, int n_in,
                              void* d_out, int out_size, void* d_ws, size_t ws_size,
                              hipStream_t stream)
{
    const float* ego   = (const float*)d_in[0];
    const float* rel   = (const float*)d_in[1];
    const int*   row   = (const int*)  d_in[2];
    const int*   col   = (const int*)  d_in[3];
    const float* vals  = (const float*)d_in[4];
    const int*   row_r = (const int*)  d_in[5];
    const int*   rel_i = (const int*)  d_in[6];
    const float* vals_r= (const float*)d_in[7];
    const float* W1    = (const float*)d_in[8];
    const float* b1    = (const float*)d_in[9];
    const float* W2    = (const float*)d_in[10];
    const float* b2    = (const float*)d_in[11];
    float* out = (float*)d_out;

    int*   offsets = (int*)d_ws;                       // NN
    int*   bsums   = offsets + NN;                     // 128
    float* coeff   = (float*)(bsums + 128);            // NN*NR
    u64*   recs    = (u64*)(coeff + (size_t)NN * NR);  // NE (8B-aligned)

    // zero offsets + bsums + coeff (contiguous prefix)
    size_t zero_bytes = ((size_t)NN + 128 + (size_t)NN * NR) * sizeof(int);
    hipMemsetAsync(d_ws, 0, zero_bytes, stream);

    int eblocks = (NE + 255) / 256;                    // 12500
    hist_kernel<<<eblocks, 256, 0, stream>>>(row, row_r, rel_i, vals_r,
                                             offsets, coeff);
    scan1_kernel<<<NBLK_SCAN, SCAN_BLK, 0, stream>>>(offsets, bsums);
    scan2_kernel<<<1, 128, 0, stream>>>(bsums);
    scan3_kernel<<<NBLK_SCAN, SCAN_BLK, 0, stream>>>(offsets, bsums);
    scatter_kernel<<<eblocks, 256, 0, stream>>>(row, col, vals,
                                                offsets, recs);
    int gblocks = (NN + 15) / 16;                      // 6250
    gather_finalize_kernel<<<gblocks, 256, 0, stream>>>(
        ego, rel, offsets, recs, coeff, W1, b1, W2, b2, out);
}